// Round 5
// baseline (413.230 us; speedup 1.0000x reference)
//
#include <hip/hip_runtime.h>

#define BB 16
#define NT 2048
#define NC 2048
#define DIM 256
#define INDIM 128

typedef unsigned short u16;
typedef __bf16 bfx8 __attribute__((ext_vector_type(8)));
typedef __bf16 bfx8a __attribute__((ext_vector_type(8), aligned(8)));
typedef float f32x4 __attribute__((ext_vector_type(4)));

__device__ __forceinline__ u16 f2bf(float f) {
    union { float f; unsigned u; } v; v.f = f;
    return (u16)((v.u + 0x7FFFu + ((v.u >> 16) & 1u)) >> 16);
}

#define MFMA16(a, b, c) __builtin_amdgcn_mfma_f32_16x16x32_bf16((a), (b), (c), 0, 0, 0)

// ---------------- converts ----------------

// all six weight transposes in ONE launch: w[K][256] fp32 -> wt[256][K] bf16
__global__ void cvt_w_all(const float* __restrict__ w0, const float* __restrict__ w1,
                          const float* __restrict__ w2, const float* __restrict__ w3,
                          const float* __restrict__ w4, const float* __restrict__ w5,
                          u16* __restrict__ o0, u16* __restrict__ o1, u16* __restrict__ o2,
                          u16* __restrict__ o3, u16* __restrict__ o4, u16* __restrict__ o5) {
    int bx = blockIdx.x;
    const float* src; u16* dst; int K, base;
    if (bx < 128)       { src = w0; dst = o0; K = 128; base = 0; }
    else if (bx < 384)  { src = w1; dst = o1; K = 256; base = 128; }
    else if (bx < 640)  { src = w2; dst = o2; K = 256; base = 384; }
    else if (bx < 768)  { src = w3; dst = o3; K = 128; base = 640; }
    else if (bx < 1024) { src = w4; dst = o4; K = 256; base = 768; }
    else                { src = w5; dst = o5; K = 256; base = 1024; }
    int idx = (bx - base) * 256 + threadIdx.x;
    int n = idx / K, k = idx - n * K;
    dst[idx] = f2bf(src[k * 256 + n]);
}

// r [B][NC][DIM] fp32 -> rt [B][DIM][NC] bf16
__global__ void cvt_rt_kernel(const float* __restrict__ r, u16* __restrict__ rt) {
    __shared__ u16 tile[32][33];
    int b = blockIdx.z;
    int c0 = blockIdx.x * 32, d0 = blockIdx.y * 32;
    int tx = threadIdx.x, ty = threadIdx.y; // (32, 8)
    const float* rb = r + (size_t)b * NC * DIM;
#pragma unroll
    for (int i = 0; i < 4; i++) {
        int c = c0 + ty + i * 8;
        tile[ty + i * 8][tx] = f2bf(rb[(size_t)c * DIM + d0 + tx]);
    }
    __syncthreads();
    u16* rtb = rt + (size_t)b * DIM * NC;
#pragma unroll
    for (int i = 0; i < 4; i++) {
        int d = d0 + ty + i * 8;
        rtb[(size_t)d * NC + c0 + tx] = tile[tx][ty + i * 8];
    }
}

// ---------------- fused MLP layer: C[M,256] = act(A[M,K] @ Wt[256,K]^T + b) --------------

template <int K, bool RELU, bool CVTIN>
__global__ __launch_bounds__(256) void mlp_gemm(const void* __restrict__ Aq, const void* __restrict__ Ak,
                                                const u16* __restrict__ Wq, const u16* __restrict__ Wk,
                                                const float* __restrict__ bq, const float* __restrict__ bk,
                                                u16* __restrict__ Cq, u16* __restrict__ Ck) {
    constexpr int ROWB = K * 2;          // A-tile row bytes (bf16)
    constexpr int NCH = K / 16;          // 16B chunks per thread
    __shared__ __align__(16) u16 at[128 * K];

    int tid = threadIdx.x, lane = tid & 63, w = tid >> 6;
    int lr = lane & 15, lg = lane >> 4;
    int m0 = blockIdx.x * 128;
    bool isq = (blockIdx.y == 0);
    const u16* Wt = isq ? Wq : Wk;
    const float* bias = isq ? bq : bk;
    u16* C = isq ? Cq : Ck;

    if (CVTIN) {
        const float* A = (const float*)(isq ? Aq : Ak) + (size_t)m0 * K;
#pragma unroll
        for (int j = 0; j < NCH; j++) {
            int bo = tid * (NCH * 16) + j * 16;
            int row = bo >> 8;                        // K=128: 256 B rows
            int ir = bo & (ROWB - 1);
            const float* src = A + (size_t)row * K + (ir >> 1);
            float4 f0 = *reinterpret_cast<const float4*>(src);
            float4 f1 = *reinterpret_cast<const float4*>(src + 4);
            union { u16 u[8]; uint4 v; } pk;
            {
                __bf16 h;
                h = (__bf16)f0.x; pk.u[0] = *(u16*)&h;
                h = (__bf16)f0.y; pk.u[1] = *(u16*)&h;
                h = (__bf16)f0.z; pk.u[2] = *(u16*)&h;
                h = (__bf16)f0.w; pk.u[3] = *(u16*)&h;
                h = (__bf16)f1.x; pk.u[4] = *(u16*)&h;
                h = (__bf16)f1.y; pk.u[5] = *(u16*)&h;
                h = (__bf16)f1.z; pk.u[6] = *(u16*)&h;
                h = (__bf16)f1.w; pk.u[7] = *(u16*)&h;
            }
            int dst = row * ROWB + (ir ^ ((row & 7) << 4));
            *reinterpret_cast<uint4*>((char*)at + dst) = pk.v;
        }
    } else {
        const char* A = (const char*)((const u16*)(isq ? Aq : Ak) + (size_t)m0 * K);
#pragma unroll
        for (int j = 0; j < NCH; j++) {
            int bo = j * 4096 + tid * 16;
            int row = bo >> 9;                        // K=256: 512 B rows
            int ir = bo & (ROWB - 1);
            int sir = ir ^ ((row & 7) << 4);
            __builtin_amdgcn_global_load_lds(
                (const __attribute__((address_space(1))) void*)(A + (size_t)row * ROWB + sir),
                (__attribute__((address_space(3))) void*)((char*)at + bo),
                16, 0, 0);
        }
    }
    __syncthreads();

    int n0 = w * 64;
    f32x4 acc[8][4] = {};
#pragma unroll
    for (int ks = 0; ks < K / 32; ks++) {
        bfx8 b[4];
#pragma unroll
        for (int nt = 0; nt < 4; nt++)
            b[nt] = *reinterpret_cast<const bfx8*>(Wt + (size_t)(n0 + nt * 16 + lr) * K + ks * 32 + lg * 8);
#pragma unroll
        for (int mt = 0; mt < 8; mt++) {
            int row = mt * 16 + lr;
            int ir = (ks * 64 + lg * 16) ^ ((lr & 7) << 4);
            bfx8 a = *reinterpret_cast<const bfx8*>((const char*)at + row * ROWB + ir);
#pragma unroll
            for (int nt = 0; nt < 4; nt++)
                acc[mt][nt] = MFMA16(a, b[nt], acc[mt][nt]);
        }
    }

#pragma unroll
    for (int nt = 0; nt < 4; nt++) {
        int col = n0 + nt * 16 + lr;
        float bv = bias[col];
#pragma unroll
        for (int mt = 0; mt < 8; mt++) {
            int rowb = m0 + mt * 16 + lg * 4;
#pragma unroll
            for (int r = 0; r < 4; r++) {
                float v = acc[mt][nt][r] + bv;
                if (RELU) v = fmaxf(v, 0.0f);
                C[(size_t)(rowb + r) * 256 + col] = f2bf(v);
            }
        }
    }
}

// ---------------- pass 1: column stats -> gs[c] = (m_c * log2e/16, 1/l_c) ----------------
// Deferred cross-lane reduce: no shfl in the t-loop; per-lane (m,l) running stats,
// combined across lane-groups once at the end (exp2 domain throughout).

__global__ __launch_bounds__(256) void stats_kernel(const u16* __restrict__ q,
                                                    const u16* __restrict__ k,
                                                    float2* __restrict__ gso) {
    int flat = blockIdx.x;
    int sw = (flat & 7) * 64 + (flat >> 3);   // bijective XCD swizzle: 2 batches/XCD
    int b = sw >> 5;
    int c0 = (sw & 31) * 64;
    int tid = threadIdx.x, lane = tid & 63, w = tid >> 6;
    int lr = lane & 15, lg = lane >> 4;
    const u16* qb = q + (size_t)b * NT * DIM;
    const u16* kb = k + (size_t)b * NC * DIM;
    const float A2 = 1.44269504f / 16.0f;    // log2e * scale

    bfx8 kf[4][8];
#pragma unroll
    for (int j = 0; j < 4; j++)
#pragma unroll
        for (int ks = 0; ks < 8; ks++)
            kf[j][ks] = *reinterpret_cast<const bfx8*>(kb + (size_t)(c0 + j * 16 + lr) * DIM + ks * 32 + lg * 8);

    float m_run[4], l_run[4];
#pragma unroll
    for (int j = 0; j < 4; j++) { m_run[j] = -1e30f; l_run[j] = 0.0f; }

    for (int ts = 0; ts < NT / 64; ts++) {
        int t0 = ts * 64 + w * 16;
        f32x4 acc[4] = {};
#pragma unroll
        for (int ks = 0; ks < 8; ks++) {
            bfx8 a = *reinterpret_cast<const bfx8*>(qb + (size_t)(t0 + lr) * DIM + ks * 32 + lg * 8);
#pragma unroll
            for (int j = 0; j < 4; j++)
                acc[j] = MFMA16(a, kf[j][ks], acc[j]);
        }
#pragma unroll
        for (int j = 0; j < 4; j++) {
            f32x4 a = acc[j];
            float mx = fmaxf(fmaxf(a[0], a[1]), fmaxf(a[2], a[3]));
            float mn = fmaxf(m_run[j], mx);
            float t = mn * A2;
            float sum = exp2f(fmaf(a[0], A2, -t)) + exp2f(fmaf(a[1], A2, -t)) +
                        exp2f(fmaf(a[2], A2, -t)) + exp2f(fmaf(a[3], A2, -t));
            l_run[j] = l_run[j] * exp2f(fmaf(m_run[j], A2, -t)) + sum;
            m_run[j] = mn;
        }
    }

    // intra-wave combine across the 4 lane-groups (rows), once
#pragma unroll
    for (int j = 0; j < 4; j++) {
        float m = m_run[j], l = l_run[j];
#pragma unroll
        for (int d = 16; d < 64; d <<= 1) {
            float mo = __shfl_xor(m, d);
            float lo = __shfl_xor(l, d);
            float mn = fmaxf(m, mo);
            l = l * exp2f((m - mn) * A2) + lo * exp2f((mo - mn) * A2);
            m = mn;
        }
        m_run[j] = m; l_run[j] = l;
    }

    __shared__ float sm[4][64], sl[4][64];
    if (lg == 0) {
#pragma unroll
        for (int j = 0; j < 4; j++) {
            sm[w][j * 16 + lr] = m_run[j];
            sl[w][j * 16 + lr] = l_run[j];
        }
    }
    __syncthreads();
    if (tid < 64) {
        float mf = sm[0][tid];
#pragma unroll
        for (int ww = 1; ww < 4; ww++) mf = fmaxf(mf, sm[ww][tid]);
        float lf = 0.0f;
#pragma unroll
        for (int ww = 0; ww < 4; ww++) lf += sl[ww][tid] * exp2f((sm[ww][tid] - mf) * A2);
        gso[(size_t)b * NC + c0 + tid] = make_float2(mf * A2, 1.0f / lf);
    }
}

// ---------------- pass 2: 8-wave pipelined attention output ----------
// 512 thr / 8 waves, 64-row t-tile, 2 blocks/CU -> 16 waves/CU.
// S: 8 quarters 16x16 (wave w: rows 16*(w&3), cols 16*(w>>2)).
// PV: wave w: out rows 32*(w&1), cols 64*(w>>1). gs from global (prefetched).

__global__ __launch_bounds__(512, 4) void attn_kernel(const u16* __restrict__ q,
                                                      const u16* __restrict__ k,
                                                      const u16* __restrict__ rt,
                                                      const float2* __restrict__ gsg_,
                                                      float* __restrict__ out) {
    int flat = blockIdx.x;
    int sw = (flat & 7) * 64 + (flat >> 3);   // 2 batches per XCD
    int b = sw >> 5;
    int t0 = (sw & 31) * 64;
    int tid = threadIdx.x, lane = tid & 63, w = tid >> 6;
    int lr = lane & 15, lg = lane >> 4;
    int sr = w & 3, sc = w >> 2;              // S quarter
    int pr = w & 1, pc = w >> 1;              // PV split
    const u16* qb = q + (size_t)b * NT * DIM;
    const u16* kb = k + (size_t)b * NC * DIM;
    const u16* rtb = rt + (size_t)b * DIM * NC;
    const float2* gsg = gsg_ + (size_t)b * NC;

    __shared__ __align__(16) u16 kt[2][32 * 256];   // 2 x 16 KB swizzled K tiles
    __shared__ u16 pl[64][36];                      // P tile, 72 B rows

#define STAGE(nb, cc) do {                                                          \
    const u16* ksrc_ = kb + (size_t)(cc) * DIM;                                     \
    _Pragma("unroll")                                                               \
    for (int i_ = 0; i_ < 2; i_++) {                                                \
        int off_ = ((w * 2 + i_) << 10) + (lane << 4);                              \
        int row_ = off_ >> 9;                                                       \
        int ss_  = ((off_ >> 4) & 31) ^ (row_ & 7);                                 \
        const u16* g_ = ksrc_ + row_ * DIM + ss_ * 8;                               \
        __builtin_amdgcn_global_load_lds(                                           \
            (const __attribute__((address_space(1))) void*)g_,                      \
            (__attribute__((address_space(3))) void*)(&kt[nb][(w * 2 + i_) << 9]),  \
            16, 0, 0);                                                              \
    }                                                                               \
} while (0)

    // prologue: stage tile 0 (2), gs (1), rb (4), aq (8) -> vmcnt(13) drains stage only
    STAGE(0, 0);
    __builtin_amdgcn_sched_barrier(0);
    float2 gs_c, gs_n;
    gs_c = gsg[sc * 16 + lr];
    bfx8 rb_c[4], rb_n[4];
#pragma unroll
    for (int nt = 0; nt < 4; nt++)
        rb_c[nt] = *reinterpret_cast<const bfx8*>(rtb + (size_t)(pc * 64 + nt * 16 + lr) * NC + lg * 8);
    bfx8 aq[8];
#pragma unroll
    for (int ks = 0; ks < 8; ks++)
        aq[ks] = *reinterpret_cast<const bfx8*>(qb + (size_t)(t0 + sr * 16 + lr) * DIM + ks * 32 + lg * 8);
    __builtin_amdgcn_sched_barrier(0);
    asm volatile("s_waitcnt vmcnt(13)");
    __builtin_amdgcn_s_barrier();
    __builtin_amdgcn_sched_barrier(0);

    const float A = 1.44269504f / 16.0f;
    const int key = lr & 7;
    f32x4 acc[2][4] = {};
    int cur = 0;

    for (int c0 = 0; c0 < NC; c0 += 32) {
        const bool last = (c0 + 32 >= NC);
        if (!last) STAGE(cur ^ 1, c0 + 32);
        __builtin_amdgcn_sched_barrier(0);
        if (!last) {
            gs_n = gsg[c0 + 32 + sc * 16 + lr];
#pragma unroll
            for (int nt = 0; nt < 4; nt++)
                rb_n[nt] = *reinterpret_cast<const bfx8*>(rtb + (size_t)(pc * 64 + nt * 16 + lr) * NC + (c0 + 32) + lg * 8);
        }

        // S quarter: 8 MFMAs from swizzled kt[cur]
        f32x4 s = {};
        {
            const char* kc = (const char*)&kt[cur][0];
#pragma unroll
            for (int ks = 0; ks < 8; ks++) {
                int slot = (ks << 2) | lg;
                bfx8 kf = *reinterpret_cast<const bfx8*>(kc + ((sc * 16 + lr) << 9) + ((slot ^ key) << 4));
                s = MFMA16(aq[ks], kf, s);
            }
        }
        // P = exp2(S*A - m') * invl -> LDS quarter
#pragma unroll
        for (int r = 0; r < 4; r++) {
            float p = exp2f(fmaf(s[r], A, -gs_c.x)) * gs_c.y;
            __bf16 h = (__bf16)p;
            pl[sr * 16 + lg * 4 + r][sc * 16 + lr] = *(u16*)&h;
        }
        __builtin_amdgcn_sched_barrier(0);
        asm volatile("s_waitcnt lgkmcnt(0)");
        __builtin_amdgcn_s_barrier();
        __builtin_amdgcn_sched_barrier(0);

        // PV: 8 MFMAs (2 row-tiles x 4 col-tiles)
#pragma unroll
        for (int mt = 0; mt < 2; mt++) {
            bfx8a pa = *reinterpret_cast<const bfx8a*>((const char*)pl + (pr * 32 + mt * 16 + lr) * 72 + lg * 16);
#pragma unroll
            for (int nt = 0; nt < 4; nt++)
                acc[mt][nt] = MFMA16((bfx8)pa, rb_c[nt], acc[mt][nt]);
        }

        // stage drain (vmcnt(5) keeps gs_n + rb_n in flight) + P-recycle barrier
        __builtin_amdgcn_sched_barrier(0);
        asm volatile("s_waitcnt vmcnt(5) lgkmcnt(0)");
        __builtin_amdgcn_s_barrier();
        __builtin_amdgcn_sched_barrier(0);

#pragma unroll
        for (int nt = 0; nt < 4; nt++) rb_c[nt] = rb_n[nt];
        gs_c = gs_n;
        cur ^= 1;
    }
#undef STAGE

    float* ob = out + (size_t)b * NT * DIM;
#pragma unroll
    for (int mt = 0; mt < 2; mt++) {
#pragma unroll
        for (int nt = 0; nt < 4; nt++) {
            int col = pc * 64 + nt * 16 + lr;
            int rowb = t0 + pr * 32 + mt * 16 + lg * 4;
#pragma unroll
            for (int r = 0; r < 4; r++)
                ob[(size_t)(rowb + r) * DIM + col] = acc[mt][nt][r];
        }
    }
}

// ---------------- launch ----------------

extern "C" void kernel_launch(void* const* d_in, const int* in_sizes, int n_in,
                              void* d_out, int out_size, void* d_ws, size_t ws_size,
                              hipStream_t stream) {
    const float* xc  = (const float*)d_in[0];
    const float* xt  = (const float*)d_in[1];
    const float* ri  = (const float*)d_in[2];
    const float* qw1 = (const float*)d_in[3];  const float* qb1 = (const float*)d_in[4];
    const float* qw2 = (const float*)d_in[5];  const float* qb2 = (const float*)d_in[6];
    const float* qw3 = (const float*)d_in[7];  const float* qb3 = (const float*)d_in[8];
    const float* kw1 = (const float*)d_in[9];  const float* kb1 = (const float*)d_in[10];
    const float* kw2 = (const float*)d_in[11]; const float* kb2 = (const float*)d_in[12];
    const float* kw3 = (const float*)d_in[13]; const float* kb3 = (const float*)d_in[14];

    if (ws_size < ((size_t)66 << 20)) return;  // need ~65.2 MB

    char* ws = (char*)d_ws;
    u16* h1q = (u16*)(ws);
    u16* h1k = (u16*)(ws + ((size_t)16 << 20));
    u16* q   = h1q;
    u16* kk  = h1k;
    u16* h2q = (u16*)(ws + ((size_t)32 << 20));
    u16* h2k = (u16*)(ws + ((size_t)48 << 20));
    u16* rt  = h2q;
    float2* gsb = (float2*)(ws + ((size_t)64 << 20));          // 256 KB
    u16* wbuf = (u16*)(ws + ((size_t)64 << 20) + (512 << 10)); // 640 KB
    u16* qw1t = wbuf;
    u16* qw2t = qw1t + 32768;
    u16* qw3t = qw2t + 65536;
    u16* kw1t = qw3t + 65536;
    u16* kw2t = kw1t + 32768;
    u16* kw3t = kw2t + 65536;

    // weights -> transposed bf16 (one launch)
    cvt_w_all<<<dim3(1280), 256, 0, stream>>>(qw1, qw2, qw3, kw1, kw2, kw3,
                                              qw1t, qw2t, qw3t, kw1t, kw2t, kw3t);

    // fused MLP (q and k paths in one launch via blockIdx.y)
    mlp_gemm<128, true,  true ><<<dim3(256, 2), 256, 0, stream>>>(xt, xc, qw1t, kw1t, qb1, kb1, h1q, h1k);
    mlp_gemm<256, true,  false><<<dim3(256, 2), 256, 0, stream>>>(h1q, h1k, qw2t, kw2t, qb2, kb2, h2q, h2k);
    mlp_gemm<256, false, false><<<dim3(256, 2), 256, 0, stream>>>(h2q, h2k, qw3t, kw3t, qb3, kb3, q, kk);

    // r_i -> rt
    cvt_rt_kernel<<<dim3(64, 8, BB), dim3(32, 8), 0, stream>>>(ri, rt);

    // pass 1: column stats
    stats_kernel<<<dim3(512), 256, 0, stream>>>(q, kk, gsb);

    // pass 2: attention output
    attn_kernel<<<dim3(512), 512, 0, stream>>>(q, kk, rt, gsb, (float*)d_out);
}